// Round 2
// baseline (2543.963 us; speedup 1.0000x reference)
//
#include <hip/hip_runtime.h>
#include <math.h>

// SplineCNN on MI355X — round 2.
// Counting-sort edges by dst; per node-tile accumulate basis-weighted x[src]
// into LDS acc[T][26][Cin] via ds_add_f32 atomics (no RMW chains, no ordering
// constraints, cross-wave safe), then k-split transform: each thread-group owns
// a disjoint k-subset, reads W coalesced from global (L2-hot, redundancy 1),
// reduces partials through LDS (reusing acc space), fused bias+ELU store.

constexpr int BLK = 256;

// ---------------------------------------------------------------- preprocessing

__global__ void hist_kernel(const int* __restrict__ ei, int* __restrict__ deg, int E) {
    int e = blockIdx.x * blockDim.x + threadIdx.x;
    if (e < E) atomicAdd(&deg[ei[E + e]], 1);
}

__global__ __launch_bounds__(256) void scan_kernel(const int* __restrict__ deg,
                                                   int* __restrict__ row_start,
                                                   int* __restrict__ cursor,
                                                   float* __restrict__ invdeg, int n) {
    __shared__ int wsum[4];
    int tid = threadIdx.x, lane = tid & 63, wave = tid >> 6;
    int carry = 0;
    for (int base = 0; base < n; base += 2048) {
        int idx0 = base + tid * 8;
        int v[8], pre[8];
        int s = 0;
        #pragma unroll
        for (int u = 0; u < 8; ++u) {
            int id = idx0 + u;
            v[u] = (id < n) ? deg[id] : 0;
            pre[u] = s;
            s += v[u];
        }
        int inc = s;
        #pragma unroll
        for (int off = 1; off < 64; off <<= 1) {
            int t = __shfl_up(inc, off);
            if (lane >= off) inc += t;
        }
        if (lane == 63) wsum[wave] = inc;
        __syncthreads();
        int woff = 0;
        for (int w2 = 0; w2 < wave; ++w2) woff += wsum[w2];
        int tot = wsum[0] + wsum[1] + wsum[2] + wsum[3];
        int eb = carry + woff + inc - s;
        #pragma unroll
        for (int u = 0; u < 8; ++u) {
            int id = idx0 + u;
            if (id < n) {
                int rs = eb + pre[u];
                row_start[id] = rs;
                cursor[id] = rs;
                invdeg[id] = 1.0f / fmaxf((float)v[u], 1.0f);
            }
        }
        carry += tot;
        __syncthreads();
    }
    if (tid == 0) row_start[n] = carry;
}

// Edge record: 32B = float4 basis (pre-scaled by 1/deg[dst]) + {src, idxpack, dst, 0}
__global__ void scatter_kernel(const int* __restrict__ ei, const float* __restrict__ pseudo,
                               const float* __restrict__ invdeg, int* __restrict__ cursor,
                               float4* __restrict__ edges, int E) {
    int e = blockIdx.x * blockDim.x + threadIdx.x;
    if (e >= E) return;
    int src = ei[e], dst = ei[E + e];
    float p0 = pseudo[2 * e], p1 = pseudo[2 * e + 1];
    float v0 = fminf(fmaxf(p0, 0.f), 1.f) * 4.f;
    float v1 = fminf(fmaxf(p1, 0.f), 1.f) * 4.f;
    int k00 = min((int)floorf(v0), 3);
    int k01 = min((int)floorf(v1), 3);
    float f0 = v0 - (float)k00, f1 = v1 - (float)k01;
    float g0 = 1.f - f0, g1 = 1.f - f1;
    float sc = invdeg[dst];
    float4 b;
    b.x = g0 * g1 * sc;
    b.y = g0 * f1 * sc;
    b.z = f0 * g1 * sc;
    b.w = f0 * f1 * sc;
    int i00 = k00 * 5 + k01;
    unsigned ip = (unsigned)i00 | ((unsigned)(i00 + 1) << 8) |
                  ((unsigned)(i00 + 5) << 16) | ((unsigned)(i00 + 6) << 24);
    int pos = atomicAdd(&cursor[dst], 1);
    edges[pos * 2] = b;
    float4 m;
    m.x = __int_as_float(src);
    m.y = __uint_as_float((int)ip);
    m.z = __int_as_float(dst);
    m.w = 0.f;
    edges[pos * 2 + 1] = m;
}

// ---------------------------------------------------------------- fused layer

template <int Cin, int Cout, int T, int BLOCK>
__global__ __launch_bounds__(BLOCK) void layer_kernel(
        const float* __restrict__ xin, const float* __restrict__ W,
        const float* __restrict__ root, const float* __restrict__ bias,
        const int* __restrict__ row_start, const float4* __restrict__ edges,
        float* __restrict__ xout, int nNodes) {
    constexpr int ACC_F = T * 26 * Cin;
    constexpr int TG = BLOCK / Cout;          // thread-groups for k-split
    constexpr int RED_F = TG * T * Cout;
    constexpr int LDS_F = (ACC_F > RED_F) ? ACC_F : RED_F;
    __shared__ __align__(16) float lds[LDS_F];

    const int tid = threadIdx.x;
    const int node0 = blockIdx.x * T;
    const int wave = tid >> 6, lane = tid & 63;
    constexpr int NW = BLOCK / 64;

    // ---- init: zero acc, load self features into slot 25
    for (int p = tid; p < ACC_F; p += BLOCK) {
        int t = p / (26 * Cin);
        int r = p - t * (26 * Cin);
        int k = r / Cin;
        int i = r - k * Cin;
        float v = 0.f;
        int n = node0 + t;
        if (k == 25 && n < nNodes) v = xin[n * Cin + i];
        lds[p] = v;
    }
    __syncthreads();

    // ---- phase A: all waves cooperatively stream the block's edge range,
    //      scatter via LDS f32 atomics (no RMW dependency chains).
    {
        const int e0 = row_start[node0];
        const int e1 = row_start[min(node0 + T, nNodes)];
        constexpr int EPW = (Cin == 8) ? 2 : 1;   // edges per wave per slot
        constexpr int U = 4;                       // unroll
        const int sub = (Cin == 8) ? (lane >> 5) : 0;
        int ch;
        if constexpr (Cin == 64) ch = lane;
        else if constexpr (Cin == 32) ch = lane & 31;
        else ch = lane & 7;

        for (int eb = e0 + wave * U * EPW; eb < e1; eb += NW * U * EPW) {
            float4 bs[U];
            int srcs[U], tts[U];
            unsigned ips[U];
            float mk[U];
            #pragma unroll
            for (int u = 0; u < U; ++u) {
                int e2 = eb + u * EPW + sub;
                bool valid = (e2 < e1);
                e2 = valid ? e2 : (e1 - 1);
                float4 b4 = edges[e2 * 2];
                float4 m4 = edges[e2 * 2 + 1];
                bs[u] = b4;
                srcs[u] = __float_as_int(m4.x);
                ips[u] = (unsigned)__float_as_int(m4.y);
                tts[u] = __float_as_int(m4.z) - node0;
                mk[u] = valid ? 1.f : 0.f;
            }
            float xv[U];
            #pragma unroll
            for (int u = 0; u < U; ++u)
                xv[u] = xin[srcs[u] * Cin + ch] * mk[u];
            #pragma unroll
            for (int u = 0; u < U; ++u) {
                float* accN = lds + tts[u] * (26 * Cin);
                unsigned ip = ips[u];
                if constexpr (Cin == 64) {
                    atomicAdd(&accN[((ip) & 255) * 64 + ch], bs[u].x * xv[u]);
                    atomicAdd(&accN[((ip >> 8) & 255) * 64 + ch], bs[u].y * xv[u]);
                    atomicAdd(&accN[((ip >> 16) & 255) * 64 + ch], bs[u].z * xv[u]);
                    atomicAdd(&accN[((ip >> 24) & 255) * 64 + ch], bs[u].w * xv[u]);
                } else if constexpr (Cin == 32) {
                    bool lo = (lane < 32);
                    unsigned shA = lo ? 0u : 16u, shB = lo ? 8u : 24u;
                    float bA = lo ? bs[u].x : bs[u].z;
                    float bB = lo ? bs[u].y : bs[u].w;
                    atomicAdd(&accN[((ip >> shA) & 255) * 32 + ch], bA * xv[u]);
                    atomicAdd(&accN[((ip >> shB) & 255) * 32 + ch], bB * xv[u]);
                } else {
                    int c = (lane >> 3) & 3;
                    float bsc = (c == 0) ? bs[u].x : (c == 1) ? bs[u].y
                              : (c == 2) ? bs[u].z : bs[u].w;
                    atomicAdd(&accN[((ip >> (8 * c)) & 255) * 8 + ch], bsc * xv[u]);
                }
            }
        }
    }
    __syncthreads();

    // ---- phase B: k-split across TG groups; W read coalesced from global
    //      (each (k,i,o) element touched exactly once per block).
    const int o = tid % Cout;
    const int tg = tid / Cout;
    float out[T];
    #pragma unroll
    for (int t = 0; t < T; ++t) out[t] = 0.f;

    for (int k = tg; k < 26; k += TG) {
        const float* wp = (k < 25) ? (W + k * Cin * Cout) : root;
        #pragma unroll
        for (int i = 0; i < Cin; i += 4) {
            float w0 = wp[(i + 0) * Cout + o];
            float w1 = wp[(i + 1) * Cout + o];
            float w2 = wp[(i + 2) * Cout + o];
            float w3 = wp[(i + 3) * Cout + o];
            #pragma unroll
            for (int t = 0; t < T; ++t) {
                const float4 a4 = *(const float4*)&lds[(t * 26 + k) * Cin + i];
                out[t] += a4.x * w0 + a4.y * w1 + a4.z * w2 + a4.w * w3;
            }
        }
    }
    __syncthreads();   // all acc reads done; reuse LDS as reduce buffer
    #pragma unroll
    for (int t = 0; t < T; ++t)
        lds[(tg * T + t) * Cout + o] = out[t];
    __syncthreads();

    for (int p = tid; p < T * Cout; p += BLOCK) {
        int t = p / Cout, oo = p - t * Cout;
        int n = node0 + t;
        if (n < nNodes) {
            float s = bias[oo];
            #pragma unroll
            for (int g = 0; g < TG; ++g) s += lds[(g * T + t) * Cout + oo];
            s = (s > 0.f) ? s : expm1f(s);
            xout[n * Cout + oo] = s;
        }
    }
}

// ---------------------------------------------------------------- pooling + head

__global__ void pool_kernel(const float* __restrict__ h, const int* __restrict__ batch,
                            float* __restrict__ pooled, float* __restrict__ cnt, int n) {
    int gw = (blockIdx.x * blockDim.x + threadIdx.x) >> 6;
    int lane = threadIdx.x & 63;
    int nw = (gridDim.x * blockDim.x) >> 6;
    int per = (n + nw - 1) / nw;
    int n0 = gw * per, n1 = min(n0 + per, n);
    if (n0 >= n1) return;
    int cur = batch[n0];
    float s = 0.f, c = 0.f;
    for (int nn = n0; nn < n1; ++nn) {
        int g = batch[nn];
        if (g != cur) {
            atomicAdd(&pooled[cur * 64 + lane], s);
            if (lane == 0) atomicAdd(&cnt[cur], c);
            s = 0.f; c = 0.f; cur = g;
        }
        s += h[nn * 64 + lane];
        c += 1.f;
    }
    atomicAdd(&pooled[cur * 64 + lane], s);
    if (lane == 0) atomicAdd(&cnt[cur], c);
}

__global__ __launch_bounds__(128) void head_kernel(const float* __restrict__ pooled,
                                                   const float* __restrict__ cnt,
                                                   const float* __restrict__ fcw,
                                                   const float* __restrict__ fcb,
                                                   float* __restrict__ outp, int G) {
    int g = threadIdx.x;
    if (g >= G) return;
    float inv = 1.f / fmaxf(cnt[g], 1.f);
    float l[30];
    float m = -1e30f;
    #pragma unroll
    for (int j = 0; j < 30; ++j) {
        float s = fcb[j];
        for (int i = 0; i < 64; ++i) s += pooled[g * 64 + i] * inv * fcw[i * 30 + j];
        l[j] = s;
        m = fmaxf(m, s);
    }
    float lse = 0.f;
    #pragma unroll
    for (int j = 0; j < 30; ++j) lse += expf(l[j] - m);
    lse = logf(lse);
    #pragma unroll
    for (int j = 0; j < 30; ++j) outp[g * 30 + j] = l[j] - m - lse;
}

// ---------------------------------------------------------------- launch

template <int Cin, int Cout, int T>
static void launch_layer(const float* xin, const float* W, const float* root, const float* bias,
                         const int* row_start, const float4* edges, float* xout, int nN,
                         hipStream_t s) {
    int nb = (nN + T - 1) / T;
    layer_kernel<Cin, Cout, T, BLK><<<nb, BLK, 0, s>>>(xin, W, root, bias, row_start, edges, xout, nN);
}

extern "C" void kernel_launch(void* const* d_in, const int* in_sizes, int n_in,
                              void* d_out, int out_size, void* d_ws, size_t ws_size,
                              hipStream_t stream) {
    const float* x = (const float*)d_in[0];
    const int* ei = (const int*)d_in[1];
    const float* ps = (const float*)d_in[2];
    const int* batch = (const int*)d_in[3];
    const float *w1 = (const float*)d_in[4], *r1 = (const float*)d_in[5], *b1 = (const float*)d_in[6];
    const float *w2 = (const float*)d_in[7], *r2 = (const float*)d_in[8], *b2 = (const float*)d_in[9];
    const float *w3 = (const float*)d_in[10], *r3 = (const float*)d_in[11], *b3 = (const float*)d_in[12];
    const float *fcw = (const float*)d_in[13], *fcb = (const float*)d_in[14];
    float* outp = (float*)d_out;

    const int nN = in_sizes[0] / 8;  // 50000
    const int E = in_sizes[1] / 2;   // 800000
    const int G = out_size / 30;     // 128

    char* wsb = (char*)d_ws;
    size_t off = 0;
    auto alloc = [&](size_t b) -> char* {
        char* p = wsb + off;
        off = (off + b + 255) & ~(size_t)255;
        return p;
    };
    int* deg = (int*)alloc((size_t)nN * 4);
    int* row_start = (int*)alloc((size_t)(nN + 1) * 4);
    int* cursor = (int*)alloc((size_t)nN * 4);
    float* invdeg = (float*)alloc((size_t)nN * 4);
    float4* edges = (float4*)alloc((size_t)E * 32);
    float* h1 = (float*)alloc((size_t)nN * 32 * 4);
    float* h2 = (float*)alloc((size_t)nN * 64 * 4);
    float* h3 = (float*)alloc((size_t)nN * 64 * 4);
    float* pooled = (float*)alloc((size_t)G * 64 * 4);
    float* cnt = (float*)alloc((size_t)G * 4);
    (void)ws_size;

    hipMemsetAsync(deg, 0, (size_t)nN * 4, stream);
    hipMemsetAsync(pooled, 0, (size_t)G * 64 * 4, stream);
    hipMemsetAsync(cnt, 0, (size_t)G * 4, stream);

    int ebk = (E + 255) / 256;
    hist_kernel<<<ebk, 256, 0, stream>>>(ei, deg, E);
    scan_kernel<<<1, 256, 0, stream>>>(deg, row_start, cursor, invdeg, nN);
    scatter_kernel<<<ebk, 256, 0, stream>>>(ei, ps, invdeg, cursor, edges, E);

    launch_layer<8, 32, 16>(x, w1, r1, b1, row_start, edges, h1, nN, stream);
    launch_layer<32, 64, 8>(h1, w2, r2, b2, row_start, edges, h2, nN, stream);
    launch_layer<64, 64, 8>(h2, w3, r3, b3, row_start, edges, h3, nN, stream);

    pool_kernel<<<128, 256, 0, stream>>>(h3, batch, pooled, cnt, nN);
    head_kernel<<<1, 128, 0, stream>>>(pooled, cnt, fcw, fcb, outp, G);
}

// Round 3
// 1254.554 us; speedup vs baseline: 2.0278x; 2.0278x over previous
//
#include <hip/hip_runtime.h>
#include <math.h>

// SplineCNN on MI355X — round 3.
// Prep: counting-sort edge-ids by dst, then expand each edge into 4 (k,src,basis)
// entries sorted by k within each node (per-wave 25-bucket counting sort).
// Layer phase A: one node per wave-slot, lanes=channels; walk the node's k-sorted
// entry list with a register running sum; ds_write the running value every entry
// (same-k entries overwrite with a more complete sum -> final LDS state exact).
// No atomics, no RMW chains. Phase B: k-split transform, W read coalesced from
// global (L2-hot), LDS reduce, fused bias+ELU.

constexpr int BLK = 512;

// ---------------------------------------------------------------- preprocessing

__global__ void hist_kernel(const int* __restrict__ ei, int* __restrict__ deg, int E) {
    int e = blockIdx.x * blockDim.x + threadIdx.x;
    if (e < E) atomicAdd(&deg[ei[E + e]], 1);
}

__global__ __launch_bounds__(256) void scan_kernel(const int* __restrict__ deg,
                                                   int* __restrict__ row_start,
                                                   int* __restrict__ cursor,
                                                   float* __restrict__ invdeg, int n) {
    __shared__ int wsum[4];
    int tid = threadIdx.x, lane = tid & 63, wave = tid >> 6;
    int carry = 0;
    for (int base = 0; base < n; base += 2048) {
        int idx0 = base + tid * 8;
        int v[8], pre[8];
        int s = 0;
        #pragma unroll
        for (int u = 0; u < 8; ++u) {
            int id = idx0 + u;
            v[u] = (id < n) ? deg[id] : 0;
            pre[u] = s;
            s += v[u];
        }
        int inc = s;
        #pragma unroll
        for (int off = 1; off < 64; off <<= 1) {
            int t = __shfl_up(inc, off);
            if (lane >= off) inc += t;
        }
        if (lane == 63) wsum[wave] = inc;
        __syncthreads();
        int woff = 0;
        for (int w2 = 0; w2 < wave; ++w2) woff += wsum[w2];
        int tot = wsum[0] + wsum[1] + wsum[2] + wsum[3];
        int eb = carry + woff + inc - s;
        #pragma unroll
        for (int u = 0; u < 8; ++u) {
            int id = idx0 + u;
            if (id < n) {
                int rs = eb + pre[u];
                row_start[id] = rs;
                cursor[id] = rs;
                invdeg[id] = 1.0f / fmaxf((float)v[u], 1.0f);
            }
        }
        carry += tot;
        __syncthreads();
    }
    if (tid == 0) row_start[n] = carry;
}

__global__ void scatter_ids(const int* __restrict__ ei, int* __restrict__ cursor,
                            int* __restrict__ eids, int E) {
    int e = blockIdx.x * blockDim.x + threadIdx.x;
    if (e >= E) return;
    int dst = ei[E + e];
    int pos = atomicAdd(&cursor[dst], 1);
    eids[pos] = e;
}

// Expand each node's edges into 4 entries each, k-sorted within the node.
// Entry: packed = (k<<16)|src (src<65536), basis pre-scaled by 1/deg.
__global__ __launch_bounds__(256) void expand_kernel(
        const int* __restrict__ ei, const float* __restrict__ pseudo,
        const float* __restrict__ invdeg, const int* __restrict__ row_start,
        const int* __restrict__ eids, int2* __restrict__ entries, int E, int nN) {
    __shared__ int hist[4][32];
    __shared__ int curs[4][32];
    int tid = threadIdx.x, w = tid >> 6, lane = tid & 63;
    int n = blockIdx.x * 4 + w;
    if (lane < 32) hist[w][lane] = 0;
    __syncthreads();
    int eb = 0, ee = 0;
    if (n < nN) { eb = row_start[n]; ee = row_start[n + 1]; }
    int deg = ee - eb;
    for (int j = lane; j < deg; j += 64) {
        int eid = eids[eb + j];
        float p0 = pseudo[2 * eid], p1 = pseudo[2 * eid + 1];
        float v0 = fminf(fmaxf(p0, 0.f), 1.f) * 4.f;
        float v1 = fminf(fmaxf(p1, 0.f), 1.f) * 4.f;
        int k00 = min((int)floorf(v0), 3);
        int k01 = min((int)floorf(v1), 3);
        int i00 = k00 * 5 + k01;
        atomicAdd(&hist[w][i00], 1);
        atomicAdd(&hist[w][i00 + 1], 1);
        atomicAdd(&hist[w][i00 + 5], 1);
        atomicAdd(&hist[w][i00 + 6], 1);
    }
    __syncthreads();
    if (lane < 25) {
        int pre = 0;
        for (int i = 0; i < lane; ++i) pre += hist[w][i];
        curs[w][lane] = pre;
    }
    __syncthreads();
    float sc = (n < nN) ? invdeg[n] : 0.f;
    int base4 = 4 * eb;
    for (int j = lane; j < deg; j += 64) {
        int eid = eids[eb + j];
        int src = ei[eid];
        float p0 = pseudo[2 * eid], p1 = pseudo[2 * eid + 1];
        float v0 = fminf(fmaxf(p0, 0.f), 1.f) * 4.f;
        float v1 = fminf(fmaxf(p1, 0.f), 1.f) * 4.f;
        int k00 = min((int)floorf(v0), 3);
        int k01 = min((int)floorf(v1), 3);
        float f0 = v0 - (float)k00, f1 = v1 - (float)k01;
        float g0 = 1.f - f0, g1 = 1.f - f1;
        int i00 = k00 * 5 + k01;
        float bs[4] = {g0 * g1 * sc, g0 * f1 * sc, f0 * g1 * sc, f0 * f1 * sc};
        int ks[4] = {i00, i00 + 1, i00 + 5, i00 + 6};
        #pragma unroll
        for (int c = 0; c < 4; ++c) {
            int pos = atomicAdd(&curs[w][ks[c]], 1);
            int2 en;
            en.x = (ks[c] << 16) | src;
            en.y = __float_as_int(bs[c]);
            entries[base4 + pos] = en;
        }
    }
}

// ---------------------------------------------------------------- fused layer

template <int Cin, int Cout, int T, int BLOCK, bool KSPLIT>
__global__ __launch_bounds__(BLOCK) void layer_kernel(
        const float* __restrict__ xin, const float* __restrict__ W,
        const float* __restrict__ root, const float* __restrict__ bias,
        const int* __restrict__ row_start, const int2* __restrict__ entries,
        float* __restrict__ xout, int nNodes) {
    constexpr int ACC_F = T * 26 * Cin;
    constexpr int TG = BLOCK / Cout;
    static_assert(!KSPLIT || (TG * T * Cout <= ACC_F), "reduce buffer fits");
    __shared__ __align__(16) float lds[ACC_F];

    const int tid = threadIdx.x;
    const int node0 = blockIdx.x * T;

    // init: zero k<25, self features at k=25
    for (int p = tid; p < ACC_F; p += BLOCK) {
        int t = p / (26 * Cin);
        int r = p - t * (26 * Cin);
        int k = r / Cin;
        int i = r - k * Cin;
        float v = 0.f;
        int n = node0 + t;
        if (k == 25 && n < nNodes) v = xin[n * Cin + i];
        lds[p] = v;
    }
    __syncthreads();

    // ---- phase A: per-node segmented sums over k-sorted entries
    {
        constexpr int SUB = 64 / Cin;
        const int wave = tid >> 6, lane = tid & 63;
        const int slot = lane / Cin, ch = lane % Cin;
        const int t = wave * SUB + slot;
        const int n = node0 + t;
        if (t < T && n < nNodes) {
            int eb = row_start[n];
            int s4 = 4 * eb;
            int len4 = 4 * (row_start[n + 1] - eb);
            if (len4 > 0) {
                float runsum = 0.f;
                int kprev = -1;
                int2 cur[4], nxt[4];
                #pragma unroll
                for (int u = 0; u < 4; ++u)
                    cur[u] = entries[s4 + ((u < len4) ? u : (len4 - 1))];
                for (int j = 0; j < len4; j += 4) {
                    float xv[4];
                    #pragma unroll
                    for (int u = 0; u < 4; ++u) {
                        int src = cur[u].x & 0xffff;
                        float m = (j + u < len4) ? 1.f : 0.f;
                        xv[u] = xin[src * Cin + ch] * m;
                    }
                    int jn = j + 4;
                    #pragma unroll
                    for (int u = 0; u < 4; ++u) {
                        int jj = jn + u;
                        jj = (jj < len4) ? jj : (len4 - 1);
                        nxt[u] = entries[s4 + jj];
                    }
                    #pragma unroll
                    for (int u = 0; u < 4; ++u) {
                        int k = cur[u].x >> 16;
                        float b = __int_as_float(cur[u].y);
                        runsum = ((k == kprev) ? runsum : 0.f) + b * xv[u];
                        lds[(t * 26 + k) * Cin + ch] = runsum;
                        kprev = k;
                    }
                    #pragma unroll
                    for (int u = 0; u < 4; ++u) cur[u] = nxt[u];
                }
            }
        }
    }
    __syncthreads();

    // ---- phase B
    const int o = tid % Cout;
    const int tg = tid / Cout;
    if constexpr (KSPLIT) {
        float out[T];
        #pragma unroll
        for (int t = 0; t < T; ++t) out[t] = 0.f;
        for (int k = tg; k < 26; k += TG) {
            const float* wp = (k < 25) ? (W + k * Cin * Cout) : root;
            #pragma unroll
            for (int i = 0; i < Cin; i += 4) {
                float w0 = wp[(i + 0) * Cout + o];
                float w1 = wp[(i + 1) * Cout + o];
                float w2 = wp[(i + 2) * Cout + o];
                float w3 = wp[(i + 3) * Cout + o];
                #pragma unroll
                for (int t = 0; t < T; ++t) {
                    const float4 a4 = *(const float4*)&lds[(t * 26 + k) * Cin + i];
                    out[t] += a4.x * w0 + a4.y * w1 + a4.z * w2 + a4.w * w3;
                }
            }
        }
        __syncthreads();
        #pragma unroll
        for (int t = 0; t < T; ++t) lds[(tg * T + t) * Cout + o] = out[t];
        __syncthreads();
        for (int p = tid; p < T * Cout; p += BLOCK) {
            int t = p / Cout, oo = p - t * Cout;
            int n = node0 + t;
            if (n < nNodes) {
                float s = bias[oo];
                #pragma unroll
                for (int g = 0; g < TG; ++g) s += lds[(g * T + t) * Cout + oo];
                s = (s > 0.f) ? s : expm1f(s);
                xout[n * Cout + oo] = s;
            }
        }
    } else {
        constexpr int TPT = T / TG;
        static_assert(TG * TPT == T, "tile mapping");
        float out[TPT];
        #pragma unroll
        for (int tt = 0; tt < TPT; ++tt) out[tt] = 0.f;
        for (int k = 0; k < 26; ++k) {
            const float* wp = (k < 25) ? (W + k * Cin * Cout) : root;
            #pragma unroll
            for (int i = 0; i < Cin; i += 4) {
                float w0 = wp[(i + 0) * Cout + o];
                float w1 = wp[(i + 1) * Cout + o];
                float w2 = wp[(i + 2) * Cout + o];
                float w3 = wp[(i + 3) * Cout + o];
                #pragma unroll
                for (int tt = 0; tt < TPT; ++tt) {
                    const float4 a4 = *(const float4*)&lds[((tg * TPT + tt) * 26 + k) * Cin + i];
                    out[tt] += a4.x * w0 + a4.y * w1 + a4.z * w2 + a4.w * w3;
                }
            }
        }
        #pragma unroll
        for (int tt = 0; tt < TPT; ++tt) {
            int n = node0 + tg * TPT + tt;
            if (n < nNodes) {
                float s = out[tt] + bias[o];
                s = (s > 0.f) ? s : expm1f(s);
                xout[n * Cout + o] = s;
            }
        }
    }
}

// ---------------------------------------------------------------- pooling + head

__global__ void pool_kernel(const float* __restrict__ h, const int* __restrict__ batch,
                            float* __restrict__ pooled, float* __restrict__ cnt, int n) {
    int gw = (blockIdx.x * blockDim.x + threadIdx.x) >> 6;
    int lane = threadIdx.x & 63;
    int nw = (gridDim.x * blockDim.x) >> 6;
    int per = (n + nw - 1) / nw;
    int n0 = gw * per, n1 = min(n0 + per, n);
    if (n0 >= n1) return;
    int cur = batch[n0];
    float s = 0.f, c = 0.f;
    for (int nn = n0; nn < n1; ++nn) {
        int g = batch[nn];
        if (g != cur) {
            atomicAdd(&pooled[cur * 64 + lane], s);
            if (lane == 0) atomicAdd(&cnt[cur], c);
            s = 0.f; c = 0.f; cur = g;
        }
        s += h[nn * 64 + lane];
        c += 1.f;
    }
    atomicAdd(&pooled[cur * 64 + lane], s);
    if (lane == 0) atomicAdd(&cnt[cur], c);
}

__global__ __launch_bounds__(128) void head_kernel(const float* __restrict__ pooled,
                                                   const float* __restrict__ cnt,
                                                   const float* __restrict__ fcw,
                                                   const float* __restrict__ fcb,
                                                   float* __restrict__ outp, int G) {
    int g = threadIdx.x;
    if (g >= G) return;
    float inv = 1.f / fmaxf(cnt[g], 1.f);
    float l[30];
    float m = -1e30f;
    #pragma unroll
    for (int j = 0; j < 30; ++j) {
        float s = fcb[j];
        for (int i = 0; i < 64; ++i) s += pooled[g * 64 + i] * inv * fcw[i * 30 + j];
        l[j] = s;
        m = fmaxf(m, s);
    }
    float lse = 0.f;
    #pragma unroll
    for (int j = 0; j < 30; ++j) lse += expf(l[j] - m);
    lse = logf(lse);
    #pragma unroll
    for (int j = 0; j < 30; ++j) outp[g * 30 + j] = l[j] - m - lse;
}

// ---------------------------------------------------------------- launch

extern "C" void kernel_launch(void* const* d_in, const int* in_sizes, int n_in,
                              void* d_out, int out_size, void* d_ws, size_t ws_size,
                              hipStream_t stream) {
    const float* x = (const float*)d_in[0];
    const int* ei = (const int*)d_in[1];
    const float* ps = (const float*)d_in[2];
    const int* batch = (const int*)d_in[3];
    const float *w1 = (const float*)d_in[4], *r1 = (const float*)d_in[5], *b1 = (const float*)d_in[6];
    const float *w2 = (const float*)d_in[7], *r2 = (const float*)d_in[8], *b2 = (const float*)d_in[9];
    const float *w3 = (const float*)d_in[10], *r3 = (const float*)d_in[11], *b3 = (const float*)d_in[12];
    const float *fcw = (const float*)d_in[13], *fcb = (const float*)d_in[14];
    float* outp = (float*)d_out;

    const int nN = in_sizes[0] / 8;  // 50000
    const int E = in_sizes[1] / 2;   // 800000
    const int G = out_size / 30;     // 128

    char* wsb = (char*)d_ws;
    size_t off = 0;
    auto alloc = [&](size_t b) -> char* {
        char* p = wsb + off;
        off = (off + b + 255) & ~(size_t)255;
        return p;
    };
    int* deg = (int*)alloc((size_t)nN * 4);
    int* row_start = (int*)alloc((size_t)(nN + 1) * 4);
    int* cursor = (int*)alloc((size_t)nN * 4);
    float* invdeg = (float*)alloc((size_t)nN * 4);
    int* eids = (int*)alloc((size_t)E * 4);
    int2* entries = (int2*)alloc((size_t)E * 4 * 8);
    float* h1 = (float*)alloc((size_t)nN * 32 * 4);
    float* h2 = (float*)alloc((size_t)nN * 64 * 4);
    float* h3 = (float*)alloc((size_t)nN * 64 * 4);
    float* pooled = (float*)alloc((size_t)G * 64 * 4);
    float* cnt = (float*)alloc((size_t)G * 4);
    (void)ws_size;

    hipMemsetAsync(deg, 0, (size_t)nN * 4, stream);
    hipMemsetAsync(pooled, 0, (size_t)G * 64 * 4, stream);
    hipMemsetAsync(cnt, 0, (size_t)G * 4, stream);

    int ebk = (E + 255) / 256;
    hist_kernel<<<ebk, 256, 0, stream>>>(ei, deg, E);
    scan_kernel<<<1, 256, 0, stream>>>(deg, row_start, cursor, invdeg, nN);
    scatter_ids<<<ebk, 256, 0, stream>>>(ei, cursor, eids, E);
    expand_kernel<<<(nN + 3) / 4, 256, 0, stream>>>(ei, ps, invdeg, row_start, eids, entries, E, nN);

    layer_kernel<8, 32, 64, BLK, false><<<(nN + 63) / 64, BLK, 0, stream>>>(
        x, w1, r1, b1, row_start, entries, h1, nN);
    layer_kernel<32, 64, 16, BLK, true><<<(nN + 15) / 16, BLK, 0, stream>>>(
        h1, w2, r2, b2, row_start, entries, h2, nN);
    layer_kernel<64, 64, 8, BLK, true><<<(nN + 7) / 8, BLK, 0, stream>>>(
        h2, w3, r3, b3, row_start, entries, h3, nN);

    pool_kernel<<<128, 256, 0, stream>>>(h3, batch, pooled, cnt, nN);
    head_kernel<<<1, 128, 0, stream>>>(pooled, cnt, fcw, fcb, outp, G);
}

// Round 4
// 818.039 us; speedup vs baseline: 3.1098x; 1.5336x over previous
//
#include <hip/hip_runtime.h>
#include <hip/hip_bf16.h>
#include <math.h>

// SplineCNN on MI355X — round 4.
// Prep: counting-sort edge-ids by dst; expand each edge into 4 (k,src,basis)
// entries k-sorted per node (+ cut4[n] = #entries with k<13 for chunking);
// transpose W (+root as k=25) to bf16 Wt[o][K] once per call.
// Layer: per 16-node tile, NH k-chunks: {zero LDS; phase A segmented-sum
// running-value overwrite into bf16 acc[t][kk][ch]; MFMA 16x16x32_bf16
// (A=acc from LDS, B=Wt from global/L2) accumulating f32 frags}; fused
// bias+ELU epilogue. LDS ~27KB -> ~6 blocks/CU.

typedef __attribute__((ext_vector_type(8))) short bf16x8;
typedef __attribute__((ext_vector_type(4))) float f32x4;

// ---------------------------------------------------------------- preprocessing

__global__ void hist_kernel(const int* __restrict__ ei, int* __restrict__ deg, int E) {
    int e = blockIdx.x * blockDim.x + threadIdx.x;
    if (e < E) atomicAdd(&deg[ei[E + e]], 1);
}

__global__ __launch_bounds__(256) void scan_kernel(const int* __restrict__ deg,
                                                   int* __restrict__ row_start,
                                                   int* __restrict__ cursor,
                                                   float* __restrict__ invdeg, int n) {
    __shared__ int wsum[4];
    int tid = threadIdx.x, lane = tid & 63, wave = tid >> 6;
    int carry = 0;
    for (int base = 0; base < n; base += 2048) {
        int idx0 = base + tid * 8;
        int v[8], pre[8];
        int s = 0;
        #pragma unroll
        for (int u = 0; u < 8; ++u) {
            int id = idx0 + u;
            v[u] = (id < n) ? deg[id] : 0;
            pre[u] = s;
            s += v[u];
        }
        int inc = s;
        #pragma unroll
        for (int off = 1; off < 64; off <<= 1) {
            int t = __shfl_up(inc, off);
            if (lane >= off) inc += t;
        }
        if (lane == 63) wsum[wave] = inc;
        __syncthreads();
        int woff = 0;
        for (int w2 = 0; w2 < wave; ++w2) woff += wsum[w2];
        int tot = wsum[0] + wsum[1] + wsum[2] + wsum[3];
        int eb = carry + woff + inc - s;
        #pragma unroll
        for (int u = 0; u < 8; ++u) {
            int id = idx0 + u;
            if (id < n) {
                int rs = eb + pre[u];
                row_start[id] = rs;
                cursor[id] = rs;
                invdeg[id] = 1.0f / fmaxf((float)v[u], 1.0f);
            }
        }
        carry += tot;
        __syncthreads();
    }
    if (tid == 0) row_start[n] = carry;
}

__global__ void scatter_ids(const int* __restrict__ ei, int* __restrict__ cursor,
                            int* __restrict__ eids, int E) {
    int e = blockIdx.x * blockDim.x + threadIdx.x;
    if (e >= E) return;
    int dst = ei[E + e];
    int pos = atomicAdd(&cursor[dst], 1);
    eids[pos] = e;
}

// Entry: x = (k<<16)|src, y = basis (pre-scaled by 1/deg). k-sorted per node.
__global__ __launch_bounds__(256) void expand_kernel(
        const int* __restrict__ ei, const float* __restrict__ pseudo,
        const float* __restrict__ invdeg, const int* __restrict__ row_start,
        const int* __restrict__ eids, int2* __restrict__ entries,
        int* __restrict__ cut4, int E, int nN) {
    __shared__ int hist[4][32];
    __shared__ int curs[4][32];
    int tid = threadIdx.x, w = tid >> 6, lane = tid & 63;
    int n = blockIdx.x * 4 + w;
    if (lane < 32) hist[w][lane] = 0;
    __syncthreads();
    int eb = 0, ee = 0;
    if (n < nN) { eb = row_start[n]; ee = row_start[n + 1]; }
    int deg = ee - eb;
    for (int j = lane; j < deg; j += 64) {
        int eid = eids[eb + j];
        float p0 = pseudo[2 * eid], p1 = pseudo[2 * eid + 1];
        float v0 = fminf(fmaxf(p0, 0.f), 1.f) * 4.f;
        float v1 = fminf(fmaxf(p1, 0.f), 1.f) * 4.f;
        int k00 = min((int)floorf(v0), 3);
        int k01 = min((int)floorf(v1), 3);
        int i00 = k00 * 5 + k01;
        atomicAdd(&hist[w][i00], 1);
        atomicAdd(&hist[w][i00 + 1], 1);
        atomicAdd(&hist[w][i00 + 5], 1);
        atomicAdd(&hist[w][i00 + 6], 1);
    }
    __syncthreads();
    if (lane < 25) {
        int pre = 0;
        for (int i = 0; i < lane; ++i) pre += hist[w][i];
        curs[w][lane] = pre;
        if (lane == 13 && n < nN) cut4[n] = pre;   // # entries with k<13
    }
    __syncthreads();
    float sc = (n < nN) ? invdeg[n] : 0.f;
    int base4 = 4 * eb;
    for (int j = lane; j < deg; j += 64) {
        int eid = eids[eb + j];
        int src = ei[eid];
        float p0 = pseudo[2 * eid], p1 = pseudo[2 * eid + 1];
        float v0 = fminf(fmaxf(p0, 0.f), 1.f) * 4.f;
        float v1 = fminf(fmaxf(p1, 0.f), 1.f) * 4.f;
        int k00 = min((int)floorf(v0), 3);
        int k01 = min((int)floorf(v1), 3);
        float f0 = v0 - (float)k00, f1 = v1 - (float)k01;
        float g0 = 1.f - f0, g1 = 1.f - f1;
        int i00 = k00 * 5 + k01;
        float bs[4] = {g0 * g1 * sc, g0 * f1 * sc, f0 * g1 * sc, f0 * f1 * sc};
        int ks[4] = {i00, i00 + 1, i00 + 5, i00 + 6};
        #pragma unroll
        for (int c = 0; c < 4; ++c) {
            int pos = atomicAdd(&curs[w][ks[c]], 1);
            int2 en;
            en.x = (ks[c] << 16) | src;
            en.y = __float_as_int(bs[c]);
            entries[base4 + pos] = en;
        }
    }
}

// Wt[o][KW] bf16 from W[k][i][o] f32 (k=25 -> root), zero-padded to KW.
template <int Cin, int Cout, int KW>
__global__ void wprep_kernel(const float* __restrict__ W, const float* __restrict__ root,
                             __hip_bfloat16* __restrict__ Wt) {
    int idx = blockIdx.x * 256 + threadIdx.x;
    if (idx >= Cout * KW) return;
    int o = idx / KW, kk = idx - o * KW;
    float v = 0.f;
    if (kk < 26 * Cin) {
        int k = kk / Cin, i = kk - k * Cin;
        v = (k < 25) ? W[(k * Cin + i) * Cout + o] : root[i * Cout + o];
    }
    Wt[idx] = __float2bfloat16(v);
}

// ---------------------------------------------------------------- fused layer

// T nodes/block, 256 threads (4 waves). NH k-chunks; KE = padded K elems/chunk.
template <int Cin, int Cout, int T, int NH, int KE>
__global__ __launch_bounds__(256) void layer_kernel(
        const float* __restrict__ xin, const __hip_bfloat16* __restrict__ Wt,
        const float* __restrict__ bias, const int* __restrict__ row_start,
        const int* __restrict__ cut4, const int2* __restrict__ entries,
        float* __restrict__ xout, int nNodes) {
    constexpr int STRIDE = KE + 8;              // bf16 elems per node row (+16B pad)
    constexpr int KW = NH * KE;                  // Wt row length
    constexpr int SPW = 64 / Cin;                // node-slots per wave
    constexpr int S = 4 * SPW;                   // slots per block
    constexpr int NPS = T / S;                   // nodes per slot
    static_assert(NPS * S == T, "slot mapping");
    constexpr int NT = Cout / 16, MT = T / 16;
    static_assert(NT * MT == 4, "4 waves = MT x NT tiles");
    constexpr int ROOTKK = 25 - (NH - 1) * 13;   // kk slot of root/self within last chunk

    __shared__ __hip_bfloat16 acc[T * STRIDE];

    const int tid = threadIdx.x;
    const int node0 = blockIdx.x * T;
    const int wave = tid >> 6, lane = tid & 63;
    const int slot = (SPW > 1) ? (lane / Cin) : 0;
    const int ch = lane & (Cin - 1);
    const int sIdx = wave * SPW + slot;
    const int mt = wave / NT, nt = wave % NT;
    const int r16 = lane & 15, g8 = lane >> 4;

    f32x4 dacc = {0.f, 0.f, 0.f, 0.f};

    for (int c = 0; c < NH; ++c) {
        // zero acc
        for (int p = tid; p < T * STRIDE / 2; p += 256)
            ((unsigned*)acc)[p] = 0;
        __syncthreads();
        // self features into root slot (last chunk only)
        if (c == NH - 1) {
            for (int p = tid; p < T * Cin; p += 256) {
                int t = p / Cin, i = p - t * Cin;
                int n = node0 + t;
                if (n < nNodes)
                    acc[t * STRIDE + ROOTKK * Cin + i] = __float2bfloat16(xin[n * Cin + i]);
            }
        }
        // ---- phase A: segmented running sums over k-sorted entries
        const int KB = c * 13 * ((NH > 1) ? 1 : 0) * Cin;  // elem offset of chunk base
        for (int rr = 0; rr < NPS; ++rr) {
            int t = sIdx + rr * S;
            int n = node0 + t;
            if (n >= nNodes) continue;
            int eb = row_start[n], ee = row_start[n + 1];
            int pstart, pend;
            if constexpr (NH == 2) {
                int c4 = cut4[n];
                pstart = 4 * eb + ((c == 0) ? 0 : c4);
                pend = (c == 0) ? (4 * eb + c4) : (4 * ee);
            } else {
                pstart = 4 * eb;
                pend = 4 * ee;
            }
            int cnt = pend - pstart;
            if (cnt <= 0) continue;
            const int abase = t * STRIDE + ch - KB;
            float runsum = 0.f;
            int kprev = -1;
            int nfull = cnt & ~3;
            int2 cur[4];
            if (nfull > 0) {
                #pragma unroll
                for (int u = 0; u < 4; ++u) cur[u] = entries[pstart + u];
            }
            for (int j = 0; j < nfull; j += 4) {
                float xv[4];
                #pragma unroll
                for (int u = 0; u < 4; ++u)
                    xv[u] = xin[(cur[u].x & 0xffff) * Cin + ch];
                int nb = pstart + j + 4;
                int2 nxt[4];
                #pragma unroll
                for (int u = 0; u < 4; ++u) {
                    int jj = nb + u;
                    jj = (jj < pend) ? jj : (pend - 1);
                    nxt[u] = entries[jj];
                }
                #pragma unroll
                for (int u = 0; u < 4; ++u) {
                    int k = cur[u].x >> 16;
                    float b = __int_as_float(cur[u].y);
                    runsum = ((k == kprev) ? runsum : 0.f) + b * xv[u];
                    acc[abase + k * Cin] = __float2bfloat16(runsum);
                    kprev = k;
                }
                #pragma unroll
                for (int u = 0; u < 4; ++u) cur[u] = nxt[u];
            }
            for (int j = pstart + nfull; j < pend; ++j) {
                int2 e = entries[j];
                float xv = xin[(e.x & 0xffff) * Cin + ch];
                int k = e.x >> 16;
                runsum = ((k == kprev) ? runsum : 0.f) + __int_as_float(e.y) * xv;
                acc[abase + k * Cin] = __float2bfloat16(runsum);
                kprev = k;
            }
        }
        __syncthreads();
        // ---- phase B: MFMA over this chunk; A from LDS, B from global (L2-hot)
        {
            const __hip_bfloat16* wp = Wt + (size_t)(nt * 16 + r16) * KW + c * KE;
            const __hip_bfloat16* ap = acc + (mt * 16 + r16) * STRIDE;
            #pragma unroll
            for (int s = 0; s < KE / 32; ++s) {
                bf16x8 af = *(const bf16x8*)(ap + s * 32 + g8 * 8);
                bf16x8 bf = *(const bf16x8*)(wp + s * 32 + g8 * 8);
                dacc = __builtin_amdgcn_mfma_f32_16x16x32_bf16(af, bf, dacc, 0, 0, 0);
            }
        }
        __syncthreads();
    }
    // ---- epilogue: D[row=g8*4+j][col=r16] per tile; bias + ELU + store f32
    const int o = nt * 16 + r16;
    const float bo = bias[o];
    #pragma unroll
    for (int j = 0; j < 4; ++j) {
        int row = mt * 16 + g8 * 4 + j;
        int n = node0 + row;
        if (n < nNodes) {
            float v = dacc[j] + bo;
            v = (v > 0.f) ? v : expm1f(v);
            xout[n * Cout + o] = v;
        }
    }
}

// ---------------------------------------------------------------- pooling + head

__global__ void pool_kernel(const float* __restrict__ h, const int* __restrict__ batch,
                            float* __restrict__ pooled, float* __restrict__ cnt, int n) {
    int gw = (blockIdx.x * blockDim.x + threadIdx.x) >> 6;
    int lane = threadIdx.x & 63;
    int nw = (gridDim.x * blockDim.x) >> 6;
    int per = (n + nw - 1) / nw;
    int n0 = gw * per, n1 = min(n0 + per, n);
    if (n0 >= n1) return;
    int cur = batch[n0];
    float s = 0.f, c = 0.f;
    for (int nn = n0; nn < n1; ++nn) {
        int g = batch[nn];
        if (g != cur) {
            atomicAdd(&pooled[cur * 64 + lane], s);
            if (lane == 0) atomicAdd(&cnt[cur], c);
            s = 0.f; c = 0.f; cur = g;
        }
        s += h[nn * 64 + lane];
        c += 1.f;
    }
    atomicAdd(&pooled[cur * 64 + lane], s);
    if (lane == 0) atomicAdd(&cnt[cur], c);
}

__global__ __launch_bounds__(128) void head_kernel(const float* __restrict__ pooled,
                                                   const float* __restrict__ cnt,
                                                   const float* __restrict__ fcw,
                                                   const float* __restrict__ fcb,
                                                   float* __restrict__ outp, int G) {
    int g = threadIdx.x;
    if (g >= G) return;
    float inv = 1.f / fmaxf(cnt[g], 1.f);
    float l[30];
    float m = -1e30f;
    #pragma unroll
    for (int j = 0; j < 30; ++j) {
        float s = fcb[j];
        for (int i = 0; i < 64; ++i) s += pooled[g * 64 + i] * inv * fcw[i * 30 + j];
        l[j] = s;
        m = fmaxf(m, s);
    }
    float lse = 0.f;
    #pragma unroll
    for (int j = 0; j < 30; ++j) lse += expf(l[j] - m);
    lse = logf(lse);
    #pragma unroll
    for (int j = 0; j < 30; ++j) outp[g * 30 + j] = l[j] - m - lse;
}

// ---------------------------------------------------------------- launch

extern "C" void kernel_launch(void* const* d_in, const int* in_sizes, int n_in,
                              void* d_out, int out_size, void* d_ws, size_t ws_size,
                              hipStream_t stream) {
    const float* x = (const float*)d_in[0];
    const int* ei = (const int*)d_in[1];
    const float* ps = (const float*)d_in[2];
    const int* batch = (const int*)d_in[3];
    const float *w1 = (const float*)d_in[4], *r1 = (const float*)d_in[5], *b1 = (const float*)d_in[6];
    const float *w2 = (const float*)d_in[7], *r2 = (const float*)d_in[8], *b2 = (const float*)d_in[9];
    const float *w3 = (const float*)d_in[10], *r3 = (const float*)d_in[11], *b3 = (const float*)d_in[12];
    const float *fcw = (const float*)d_in[13], *fcb = (const float*)d_in[14];
    float* outp = (float*)d_out;

    const int nN = in_sizes[0] / 8;  // 50000
    const int E = in_sizes[1] / 2;   // 800000
    const int G = out_size / 30;     // 128

    char* wsb = (char*)d_ws;
    size_t off = 0;
    auto alloc = [&](size_t b) -> char* {
        char* p = wsb + off;
        off = (off + b + 255) & ~(size_t)255;
        return p;
    };
    int* deg = (int*)alloc((size_t)nN * 4);
    int* row_start = (int*)alloc((size_t)(nN + 1) * 4);
    int* cursor = (int*)alloc((size_t)nN * 4);
    float* invdeg = (float*)alloc((size_t)nN * 4);
    int* cut4 = (int*)alloc((size_t)nN * 4);
    int* eids = (int*)alloc((size_t)E * 4);
    int2* entries = (int2*)alloc((size_t)E * 4 * 8);
    __hip_bfloat16* wt1 = (__hip_bfloat16*)alloc((size_t)32 * 224 * 2);
    __hip_bfloat16* wt2 = (__hip_bfloat16*)alloc((size_t)64 * 832 * 2);
    __hip_bfloat16* wt3 = (__hip_bfloat16*)alloc((size_t)64 * 1664 * 2);
    float* h1 = (float*)alloc((size_t)nN * 32 * 4);
    float* h2 = (float*)alloc((size_t)nN * 64 * 4);
    float* h3 = (float*)alloc((size_t)nN * 64 * 4);
    float* pooled = (float*)alloc((size_t)G * 64 * 4);
    float* cnt = (float*)alloc((size_t)G * 4);
    (void)ws_size;

    hipMemsetAsync(deg, 0, (size_t)nN * 4, stream);
    hipMemsetAsync(pooled, 0, (size_t)G * 64 * 4, stream);
    hipMemsetAsync(cnt, 0, (size_t)G * 4, stream);

    int ebk = (E + 255) / 256;
    hist_kernel<<<ebk, 256, 0, stream>>>(ei, deg, E);
    scan_kernel<<<1, 256, 0, stream>>>(deg, row_start, cursor, invdeg, nN);
    scatter_ids<<<ebk, 256, 0, stream>>>(ei, cursor, eids, E);
    expand_kernel<<<(nN + 3) / 4, 256, 0, stream>>>(ei, ps, invdeg, row_start, eids,
                                                    entries, cut4, E, nN);
    wprep_kernel<8, 32, 224><<<(32 * 224 + 255) / 256, 256, 0, stream>>>(w1, r1, wt1);
    wprep_kernel<32, 64, 832><<<(64 * 832 + 255) / 256, 256, 0, stream>>>(w2, r2, wt2);
    wprep_kernel<64, 64, 1664><<<(64 * 1664 + 255) / 256, 256, 0, stream>>>(w3, r3, wt3);

    // L1: Cin=8,Cout=32,T=32,NH=1,KE=224 (26*8=208 zero-padded)
    layer_kernel<8, 32, 32, 1, 224><<<(nN + 31) / 32, 256, 0, stream>>>(
        x, wt1, b1, row_start, cut4, entries, h1, nN);
    // L2: Cin=32,Cout=64,T=16,NH=1,KE=832
    layer_kernel<32, 64, 16, 1, 832><<<(nN + 15) / 16, 256, 0, stream>>>(
        h1, wt2, b2, row_start, cut4, entries, h2, nN);
    // L3: Cin=64,Cout=64,T=16,NH=2,KE=832 (13 k's per chunk)
    layer_kernel<64, 64, 16, 2, 832><<<(nN + 15) / 16, 256, 0, stream>>>(
        h2, wt3, b3, row_start, cut4, entries, h3, nN);

    pool_kernel<<<128, 256, 0, stream>>>(h3, batch, pooled, cnt, nN);
    head_kernel<<<1, 128, 0, stream>>>(pooled, cnt, fcw, fcb, outp, G);
}

// Round 5
// 715.468 us; speedup vs baseline: 3.5557x; 1.1434x over previous
//
#include <hip/hip_runtime.h>
#include <hip/hip_bf16.h>
#include <math.h>

// SplineCNN on MI355X — round 5.
// Counting-sort edges by dst; expand to 4 (k,src,basis) entries k-sorted per
// node (cut4[n] = #entries with k<13). Layer kernel: 512 threads (8 waves),
// wave-group g=w>>2 processes its k-half of every node's entry list in
// PARALLEL (disjoint k-regions of full-K bf16 LDS acc; segmented running-sum
// overwrite, no atomics). Phase B: split-K MFMA 16x16x32_bf16 (slice parity
// = g) + LDS reduction between wave pairs, fused bias+ELU. Masked tails write
// to a dump k-slot (k=26) that multiplies zero-padded W rows -> harmless.

typedef __attribute__((ext_vector_type(8))) short bf16x8;
typedef __attribute__((ext_vector_type(4))) float f32x4;

// ---------------------------------------------------------------- preprocessing

__global__ void hist_kernel(const int* __restrict__ ei, int* __restrict__ deg, int E) {
    int e = blockIdx.x * blockDim.x + threadIdx.x;
    if (e < E) atomicAdd(&deg[ei[E + e]], 1);
}

__global__ __launch_bounds__(256) void scan_kernel(const int* __restrict__ deg,
                                                   int* __restrict__ row_start,
                                                   int* __restrict__ cursor,
                                                   float* __restrict__ invdeg, int n) {
    __shared__ int wsum[4];
    int tid = threadIdx.x, lane = tid & 63, wave = tid >> 6;
    int carry = 0;
    for (int base = 0; base < n; base += 2048) {
        int idx0 = base + tid * 8;
        int v[8], pre[8];
        int s = 0;
        #pragma unroll
        for (int u = 0; u < 8; ++u) {
            int id = idx0 + u;
            v[u] = (id < n) ? deg[id] : 0;
            pre[u] = s;
            s += v[u];
        }
        int inc = s;
        #pragma unroll
        for (int off = 1; off < 64; off <<= 1) {
            int t = __shfl_up(inc, off);
            if (lane >= off) inc += t;
        }
        if (lane == 63) wsum[wave] = inc;
        __syncthreads();
        int woff = 0;
        for (int w2 = 0; w2 < wave; ++w2) woff += wsum[w2];
        int tot = wsum[0] + wsum[1] + wsum[2] + wsum[3];
        int eb = carry + woff + inc - s;
        #pragma unroll
        for (int u = 0; u < 8; ++u) {
            int id = idx0 + u;
            if (id < n) {
                int rs = eb + pre[u];
                row_start[id] = rs;
                cursor[id] = rs;
                invdeg[id] = 1.0f / fmaxf((float)v[u], 1.0f);
            }
        }
        carry += tot;
        __syncthreads();
    }
    if (tid == 0) row_start[n] = carry;
}

__global__ void scatter_ids(const int* __restrict__ ei, int* __restrict__ cursor,
                            int* __restrict__ eids, int E) {
    int e = blockIdx.x * blockDim.x + threadIdx.x;
    if (e >= E) return;
    int dst = ei[E + e];
    int pos = atomicAdd(&cursor[dst], 1);
    eids[pos] = e;
}

// Entry: x = (k<<16)|src, y = basis (pre-scaled by 1/deg). k-sorted per node.
__global__ __launch_bounds__(256) void expand_kernel(
        const int* __restrict__ ei, const float* __restrict__ pseudo,
        const float* __restrict__ invdeg, const int* __restrict__ row_start,
        const int* __restrict__ eids, int2* __restrict__ entries,
        int* __restrict__ cut4, int E, int nN) {
    __shared__ int hist[4][32];
    __shared__ int curs[4][32];
    int tid = threadIdx.x, w = tid >> 6, lane = tid & 63;
    int n = blockIdx.x * 4 + w;
    if (lane < 32) hist[w][lane] = 0;
    __syncthreads();
    int eb = 0, ee = 0;
    if (n < nN) { eb = row_start[n]; ee = row_start[n + 1]; }
    int deg = ee - eb;
    for (int j = lane; j < deg; j += 64) {
        int eid = eids[eb + j];
        float p0 = pseudo[2 * eid], p1 = pseudo[2 * eid + 1];
        float v0 = fminf(fmaxf(p0, 0.f), 1.f) * 4.f;
        float v1 = fminf(fmaxf(p1, 0.f), 1.f) * 4.f;
        int k00 = min((int)floorf(v0), 3);
        int k01 = min((int)floorf(v1), 3);
        int i00 = k00 * 5 + k01;
        atomicAdd(&hist[w][i00], 1);
        atomicAdd(&hist[w][i00 + 1], 1);
        atomicAdd(&hist[w][i00 + 5], 1);
        atomicAdd(&hist[w][i00 + 6], 1);
    }
    __syncthreads();
    if (lane < 25) {
        int pre = 0;
        for (int i = 0; i < lane; ++i) pre += hist[w][i];
        curs[w][lane] = pre;
        if (lane == 13 && n < nN) cut4[n] = pre;   // # entries with k<13
    }
    __syncthreads();
    float sc = (n < nN) ? invdeg[n] : 0.f;
    int base4 = 4 * eb;
    for (int j = lane; j < deg; j += 64) {
        int eid = eids[eb + j];
        int src = ei[eid];
        float p0 = pseudo[2 * eid], p1 = pseudo[2 * eid + 1];
        float v0 = fminf(fmaxf(p0, 0.f), 1.f) * 4.f;
        float v1 = fminf(fmaxf(p1, 0.f), 1.f) * 4.f;
        int k00 = min((int)floorf(v0), 3);
        int k01 = min((int)floorf(v1), 3);
        float f0 = v0 - (float)k00, f1 = v1 - (float)k01;
        float g0 = 1.f - f0, g1 = 1.f - f1;
        int i00 = k00 * 5 + k01;
        float bs[4] = {g0 * g1 * sc, g0 * f1 * sc, f0 * g1 * sc, f0 * f1 * sc};
        int ks[4] = {i00, i00 + 1, i00 + 5, i00 + 6};
        #pragma unroll
        for (int c = 0; c < 4; ++c) {
            int pos = atomicAdd(&curs[w][ks[c]], 1);
            int2 en;
            en.x = (ks[c] << 16) | src;
            en.y = __float_as_int(bs[c]);
            entries[base4 + pos] = en;
        }
    }
}

// Wt[o][KW] bf16 from W[k][i][o] f32 (k=25 -> root), zero for kk >= 26*Cin.
template <int Cin, int Cout, int KW>
__global__ void wprep_kernel(const float* __restrict__ W, const float* __restrict__ root,
                             __hip_bfloat16* __restrict__ Wt) {
    int idx = blockIdx.x * 256 + threadIdx.x;
    if (idx >= Cout * KW) return;
    int o = idx / KW, kk = idx - o * KW;
    float v = 0.f;
    if (kk < 26 * Cin) {
        int k = kk / Cin, i = kk - k * Cin;
        v = (k < 25) ? W[(k * Cin + i) * Cout + o] : root[i * Cout + o];
    }
    Wt[idx] = __float2bfloat16(v);
}

// ---------------------------------------------------------------- fused layer

template <int Cin, int Cout, int T, int KW>
__global__ __launch_bounds__(512) void layer_kernel(
        const float* __restrict__ xin, const __hip_bfloat16* __restrict__ Wt,
        const float* __restrict__ bias, const int* __restrict__ row_start,
        const int* __restrict__ cut4, const int2* __restrict__ entries,
        float* __restrict__ xout, int nNodes) {
    constexpr int LOGC = (Cin == 64) ? 6 : (Cin == 32) ? 5 : 3;
    constexpr int STRIDE = KW + 8;              // bf16 elems per row (bank skew)
    constexpr int NS = KW / 32;                 // MFMA K-slices
    constexpr int SPW = 64 / Cin;               // node-slots per wave
    constexpr int GS = 4 * SPW;                 // slots per k-half group
    constexpr int NPS = T / GS;                 // sequential nodes per slot
    static_assert(NPS * GS == T, "slot mapping");
    constexpr int MT = T / 16, NT = Cout / 16;
    static_assert(MT * NT == 4, "4 tiles");
    static_assert(27 * Cin <= KW, "dump slot inside zero-padded W");
    constexpr int RS = Cout + 4;                // reduction row stride (f32)

    __shared__ __align__(16) __hip_bfloat16 acc[T * STRIDE];

    const int tid = threadIdx.x;
    const int node0 = blockIdx.x * T;
    const int wave = tid >> 6, lane = tid & 63;
    const int g = wave >> 2, w4 = wave & 3;
    const int slot = (SPW > 1) ? (lane >> LOGC) : 0;
    const int ch = lane & (Cin - 1);
    const int r16 = lane & 15, g8 = lane >> 4;
    const int mt = w4 / NT, nt = w4 % NT;

    // ---- init: zero acc, self features at k=25
    for (int p = tid; p < T * STRIDE / 4; p += 512)
        ((uint2*)acc)[p] = make_uint2(0u, 0u);
    __syncthreads();
    for (int p = tid; p < T * Cin; p += 512) {
        int t = p >> LOGC, i = p & (Cin - 1);
        int n = node0 + t;
        if (n < nNodes)
            acc[t * STRIDE + 25 * Cin + i] = __float2bfloat16(xin[n * Cin + i]);
    }
    __syncthreads();

    // ---- phase A: parallel k-halves, segmented running sums
    for (int rr = 0; rr < NPS; ++rr) {
        int t;
        if constexpr (SPW == 1) t = w4 + 4 * rr;          // rows Δ4: bank Δ16
        else if constexpr (SPW == 2) t = w4 + 4 * slot + 8 * rr;  // slots Δ4
        else t = 8 * w4 + slot;                            // 8 slots Δ1: distinct banks
        const int n = node0 + t;
        int p0 = 0, pend = 0, cnt = 0, abase = 0;
        if (n < nNodes) {
            int eb = row_start[n], ee = row_start[n + 1];
            int c4 = cut4[n];
            p0 = 4 * eb + (g ? c4 : 0);
            pend = g ? (4 * ee) : (4 * eb + c4);
            cnt = pend - p0;
            abase = t * STRIDE + ch;
        }
        const int pm1 = max(pend - 1, 0);
        float runsum = 0.f;
        int kprev = -1;
        int2 cur[4], nxt[4];
        #pragma unroll
        for (int u = 0; u < 4; ++u) cur[u] = entries[min(p0 + u, pm1)];

        for (int jb = 0; __any(jb < cnt); jb += 4) {
            float xv[4];
            #pragma unroll
            for (int u = 0; u < 4; ++u)
                xv[u] = xin[((cur[u].x & 0xffff) << LOGC) + ch];
            #pragma unroll
            for (int u = 0; u < 4; ++u)
                nxt[u] = entries[min(p0 + jb + 4 + u, pm1)];
            if (__all(jb + 4 <= cnt)) {
                #pragma unroll
                for (int u = 0; u < 4; ++u) {
                    int k = cur[u].x >> 16;
                    float b = __int_as_float(cur[u].y);
                    runsum = ((k == kprev) ? runsum : 0.f) + b * xv[u];
                    acc[abase + (k << LOGC)] = __float2bfloat16(runsum);
                    kprev = k;
                }
            } else {
                #pragma unroll
                for (int u = 0; u < 4; ++u) {
                    int k = cur[u].x >> 16;
                    bool valid = (jb + u) < cnt;
                    float b = valid ? __int_as_float(cur[u].y) : 0.f;
                    float rs2 = ((k == kprev) ? runsum : 0.f) + b * xv[u];
                    int idx = valid ? (abase + (k << LOGC)) : (abase + (26 << LOGC));
                    acc[idx] = __float2bfloat16(rs2);
                    runsum = valid ? rs2 : runsum;
                    kprev = valid ? k : kprev;
                }
            }
            #pragma unroll
            for (int u = 0; u < 4; ++u) cur[u] = nxt[u];
        }
    }
    __syncthreads();

    // ---- phase B: split-K MFMA (slice parity = g)
    f32x4 dacc = {0.f, 0.f, 0.f, 0.f};
    {
        const __hip_bfloat16* wp = Wt + (size_t)(nt * 16 + r16) * KW;
        const __hip_bfloat16* ap = acc + (mt * 16 + r16) * STRIDE;
        #pragma unroll
        for (int j = 0; j < (NS + 1) / 2; ++j) {
            int s = 2 * j + g;
            if (s < NS) {
                bf16x8 af = *(const bf16x8*)(ap + s * 32 + g8 * 8);
                bf16x8 bf = *(const bf16x8*)(wp + s * 32 + g8 * 8);
                dacc = __builtin_amdgcn_mfma_f32_16x16x32_bf16(af, bf, dacc, 0, 0, 0);
            }
        }
    }
    __syncthreads();
    float* red = (float*)acc;
    if (g == 1) {
        #pragma unroll
        for (int j = 0; j < 4; ++j)
            red[(mt * 16 + g8 * 4 + j) * RS + nt * 16 + r16] = dacc[j];
    }
    __syncthreads();
    if (g == 0) {
        const int o = nt * 16 + r16;
        const float bo = bias[o];
        #pragma unroll
        for (int j = 0; j < 4; ++j) {
            int row = mt * 16 + g8 * 4 + j;
            int n = node0 + row;
            if (n < nNodes) {
                float v = dacc[j] + red[row * RS + o] + bo;
                v = (v > 0.f) ? v : expm1f(v);
                xout[n * Cout + o] = v;
            }
        }
    }
}

// ---------------------------------------------------------------- pooling + head

__global__ void pool_kernel(const float* __restrict__ h, const int* __restrict__ batch,
                            float* __restrict__ pooled, float* __restrict__ cnt, int n) {
    int gw = (blockIdx.x * blockDim.x + threadIdx.x) >> 6;
    int lane = threadIdx.x & 63;
    int nw = (gridDim.x * blockDim.x) >> 6;
    int per = (n + nw - 1) / nw;
    int n0 = gw * per, n1 = min(n0 + per, n);
    if (n0 >= n1) return;
    int cur = batch[n0];
    float s = 0.f, c = 0.f;
    for (int nn = n0; nn < n1; ++nn) {
        int g = batch[nn];
        if (g != cur) {
            atomicAdd(&pooled[cur * 64 + lane], s);
            if (lane == 0) atomicAdd(&cnt[cur], c);
            s = 0.f; c = 0.f; cur = g;
        }
        s += h[nn * 64 + lane];
        c += 1.f;
    }
    atomicAdd(&pooled[cur * 64 + lane], s);
    if (lane == 0) atomicAdd(&cnt[cur], c);
}

__global__ __launch_bounds__(128) void head_kernel(const float* __restrict__ pooled,
                                                   const float* __restrict__ cnt,
                                                   const float* __restrict__ fcw,
                                                   const float* __restrict__ fcb,
                                                   float* __restrict__ outp, int G) {
    int g = threadIdx.x;
    if (g >= G) return;
    float inv = 1.f / fmaxf(cnt[g], 1.f);
    float l[30];
    float m = -1e30f;
    #pragma unroll
    for (int j = 0; j < 30; ++j) {
        float s = fcb[j];
        for (int i = 0; i < 64; ++i) s += pooled[g * 64 + i] * inv * fcw[i * 30 + j];
        l[j] = s;
        m = fmaxf(m, s);
    }
    float lse = 0.f;
    #pragma unroll
    for (int j = 0; j < 30; ++j) lse += expf(l[j] - m);
    lse = logf(lse);
    #pragma unroll
    for (int j = 0; j < 30; ++j) outp[g * 30 + j] = l[j] - m - lse;
}

// ---------------------------------------------------------------- launch

extern "C" void kernel_launch(void* const* d_in, const int* in_sizes, int n_in,
                              void* d_out, int out_size, void* d_ws, size_t ws_size,
                              hipStream_t stream) {
    const float* x = (const float*)d_in[0];
    const int* ei = (const int*)d_in[1];
    const float* ps = (const float*)d_in[2];
    const int* batch = (const int*)d_in[3];
    const float *w1 = (const float*)d_in[4], *r1 = (const float*)d_in[5], *b1 = (const float*)d_in[6];
    const float *w2 = (const float*)d_in[7], *r2 = (const float*)d_in[8], *b2 = (const float*)d_in[9];
    const float *w3 = (const float*)d_in[10], *r3 = (const float*)d_in[11], *b3 = (const float*)d_in[12];
    const float *fcw = (const float*)d_in[13], *fcb = (const float*)d_in[14];
    float* outp = (float*)d_out;

    const int nN = in_sizes[0] / 8;  // 50000
    const int E = in_sizes[1] / 2;   // 800000
    const int G = out_size / 30;     // 128

    char* wsb = (char*)d_ws;
    size_t off = 0;
    auto alloc = [&](size_t b) -> char* {
        char* p = wsb + off;
        off = (off + b + 255) & ~(size_t)255;
        return p;
    };
    int* deg = (int*)alloc((size_t)nN * 4);
    int* row_start = (int*)alloc((size_t)(nN + 1) * 4);
    int* cursor = (int*)alloc((size_t)nN * 4);
    float* invdeg = (float*)alloc((size_t)nN * 4);
    int* cut4 = (int*)alloc((size_t)nN * 4);
    int* eids = (int*)alloc((size_t)E * 4);
    int2* entries = (int2*)alloc((size_t)E * 4 * 8);
    __hip_bfloat16* wt1 = (__hip_bfloat16*)alloc((size_t)32 * 224 * 2);
    __hip_bfloat16* wt2 = (__hip_bfloat16*)alloc((size_t)64 * 864 * 2);
    __hip_bfloat16* wt3 = (__hip_bfloat16*)alloc((size_t)64 * 1728 * 2);
    float* h1 = (float*)alloc((size_t)nN * 32 * 4);
    float* h2 = (float*)alloc((size_t)nN * 64 * 4);
    float* h3 = (float*)alloc((size_t)nN * 64 * 4);
    float* pooled = (float*)alloc((size_t)G * 64 * 4);
    float* cnt = (float*)alloc((size_t)G * 4);
    (void)ws_size;

    hipMemsetAsync(deg, 0, (size_t)nN * 4, stream);
    hipMemsetAsync(pooled, 0, (size_t)G * 64 * 4, stream);
    hipMemsetAsync(cnt, 0, (size_t)G * 4, stream);

    int ebk = (E + 255) / 256;
    hist_kernel<<<ebk, 256, 0, stream>>>(ei, deg, E);
    scan_kernel<<<1, 256, 0, stream>>>(deg, row_start, cursor, invdeg, nN);
    scatter_ids<<<ebk, 256, 0, stream>>>(ei, cursor, eids, E);
    expand_kernel<<<(nN + 3) / 4, 256, 0, stream>>>(ei, ps, invdeg, row_start, eids,
                                                    entries, cut4, E, nN);
    wprep_kernel<8, 32, 224><<<(32 * 224 + 255) / 256, 256, 0, stream>>>(w1, r1, wt1);
    wprep_kernel<32, 64, 864><<<(64 * 864 + 255) / 256, 256, 0, stream>>>(w2, r2, wt2);
    wprep_kernel<64, 64, 1728><<<(64 * 1728 + 255) / 256, 256, 0, stream>>>(w3, r3, wt3);

    // L1: Cin=8,Cout=32,T=32,KW=224
    layer_kernel<8, 32, 32, 224><<<(nN + 31) / 32, 512, 0, stream>>>(
        x, wt1, b1, row_start, cut4, entries, h1, nN);
    // L2: Cin=32,Cout=64,T=16,KW=864
    layer_kernel<32, 64, 16, 864><<<(nN + 15) / 16, 512, 0, stream>>>(
        h1, wt2, b2, row_start, cut4, entries, h2, nN);
    // L3: Cin=64,Cout=64,T=16,KW=1728
    layer_kernel<64, 64, 16, 1728><<<(nN + 15) / 16, 512, 0, stream>>>(
        h2, wt3, b3, row_start, cut4, entries, h3, nN);

    pool_kernel<<<128, 256, 0, stream>>>(h3, batch, pooled, cnt, nN);
    head_kernel<<<1, 128, 0, stream>>>(pooled, cnt, fcw, fcb, outp, G);
}